// Round 3
// baseline (8127.030 us; speedup 1.0000x reference)
//
#include <hip/hip_runtime.h>

#define TW    10000
#define EMBD  100
#define SEQ   80
#define U     512
#define BATCH 2048
#define RPB   16
#define NBLK  (BATCH / RPB)   // 128 blocks
#define NTHR  1024            // 16 waves/block

typedef short short8 __attribute__((ext_vector_type(8)));
typedef float f32x4 __attribute__((ext_vector_type(4)));

typedef __attribute__((address_space(1))) unsigned char GasB;
typedef __attribute__((address_space(3))) unsigned char LasB;

static __device__ __forceinline__ unsigned short f2bf(float f){
  unsigned int u = __float_as_uint(f);
  u += 0x7fffu + ((u >> 16) & 1u);   // RNE
  return (unsigned short)(u >> 16);
}
static __device__ __forceinline__ float bf2f(unsigned short h){
  return __uint_as_float(((unsigned int)h) << 16);
}
static __device__ __forceinline__ float fast_tanh(float x){
  float e = __expf(2.0f * x);        // inf-safe: saturates to +-1
  return 1.0f - 2.0f / (e + 1.0f);
}

// async global->LDS, 16B per lane, fire-and-forget (vmcnt-tracked)
static __device__ __forceinline__ void gload16(const unsigned short* g, unsigned short* l){
  __builtin_amdgcn_global_load_lds((GasB*)(g), (LasB*)(l), 16, 0, 0);
}

#define WAITVM(N) asm volatile("s_waitcnt vmcnt(" #N ")" ::: "memory")

// ---------------- proj[w][n] = b0[n] + sum_e emb[w][e] * Wx0[e][n] ----------------
__global__ void proj_kernel(const float* __restrict__ emb, const float* __restrict__ Wx0,
                            const float* __restrict__ b0, float* __restrict__ proj){
  __shared__ float es[16][EMBD];
  const int w0 = blockIdx.x * 16;
  for (int i = threadIdx.x; i < 16 * EMBD; i += 256)
    es[i / EMBD][i % EMBD] = emb[(size_t)w0 * EMBD + i];
  __syncthreads();
  const int n = threadIdx.x;   // cols n and n+256
  float accA[16], accB[16];
#pragma unroll
  for (int wi = 0; wi < 16; ++wi){ accA[wi] = 0.0f; accB[wi] = 0.0f; }
  for (int e = 0; e < EMBD; ++e){
    const float wv0 = Wx0[(size_t)e * U + n];
    const float wv1 = Wx0[(size_t)e * U + n + 256];
#pragma unroll
    for (int wi = 0; wi < 16; ++wi){
      accA[wi] += es[wi][e] * wv0;
      accB[wi] += es[wi][e] * wv1;
    }
  }
  const float bb0 = b0[n], bb1 = b0[n + 256];
  for (int wi = 0; wi < 16; ++wi){
    proj[(size_t)(w0 + wi) * U + n]       = accA[wi] + bb0;
    proj[(size_t)(w0 + wi) * U + n + 256] = accB[wi] + bb1;
  }
}

// ---------------- dst[n][kOff + k] = bf16(src[k][n]),  src is [K][N] f32 ----------------
__global__ void transpose_bf16(const float* __restrict__ src, unsigned short* __restrict__ dst,
                               int K, int N, int dstLd, int kOff){
  const int idx = blockIdx.x * 256 + threadIdx.x;
  if (idx >= K * N) return;
  const int k = idx % K, n = idx / K;
  dst[(size_t)n * dstLd + kOff + k] = f2bf(src[(size_t)k * N + n]);
}

// One GEMM segment: acc[2] += A(state LDS) @ B(weights streamed via LDS ring).
// NC chunks of 32 k each; chunk c covers k in [c*32, c*32+32).
// bp0/bp1: per-lane global base ptrs (nf=0/1 tiles), k-contiguous layout.
// stA0: A source for chunks 0..15, stA1 for 16..31 (pass stA0 twice when NC==16).
template<int NC>
static __device__ __forceinline__ void run_segment(
    const unsigned short* __restrict__ bp0, const unsigned short* __restrict__ bp1,
    const unsigned short* stA0, const unsigned short* stA1,
    unsigned short* slotBase,     // this wave's 3 x 2KB staging ring
    int aBase, int aSwz, int lane, f32x4* acc)
{
#define ISSUE_CH(c_) { unsigned short* sl_ = slotBase + ((c_) % 3) * 1024; \
    gload16(bp0 + (c_) * 32, sl_); gload16(bp1 + (c_) * 32, sl_ + 512); }
  ISSUE_CH(0)
  ISSUE_CH(1)
#pragma unroll
  for (int c = 0; c < NC; ++c){
    if (c + 2 < NC) ISSUE_CH(c + 2)
    const int rem = NC - 1 - c;
    if (rem >= 2)      WAITVM(4);
    else if (rem == 1) WAITVM(2);
    else               WAITVM(0);
    const unsigned short* sA = (NC == 16 || c < 16) ? stA0 : stA1;
    short8 a = *reinterpret_cast<const short8*>(&sA[(aBase + (c & 15) * 32) ^ aSwz]);
    const unsigned short* sl = slotBase + (c % 3) * 1024;
    short8 b0 = *reinterpret_cast<const short8*>(&sl[(size_t)lane * 8]);
    short8 b1 = *reinterpret_cast<const short8*>(&sl[512 + (size_t)lane * 8]);
    acc[0] = __builtin_amdgcn_mfma_f32_16x16x32_bf16(a, b0, acc[0], 0, 0, 0);
    acc[1] = __builtin_amdgcn_mfma_f32_16x16x32_bf16(a, b1, acc[1], 0, 0, 0);
  }
#undef ISSUE_CH
}

// ---------------- persistent per-block RNN: 16 rows through all 80 steps ----------------
__global__ __launch_bounds__(NTHR, 4)
void rnn_persist(const int* __restrict__ tokens,
                 const float* __restrict__ proj,
                 const unsigned short* __restrict__ Wh0t,
                 const unsigned short* __restrict__ W1t,
                 const unsigned short* __restrict__ W2t,
                 const float* __restrict__ b1,
                 const float* __restrict__ b2,
                 const float* __restrict__ Wout,
                 const float* __restrict__ bout,
                 float* __restrict__ out)
{
  extern __shared__ unsigned short smem[];
  unsigned short* st0 = smem;                    // 16 KiB (16 rows x 512, swizzled)
  unsigned short* st1 = smem + 8192;             // 16 KiB
  unsigned short* st2 = smem + 16384;            // 16 KiB
  unsigned short* stage = smem + 24576;          // 96 KiB: 16 waves x 3 slots x 2KB

  const int tid = threadIdx.x;
  for (int i = tid; i < 3 * 8192; i += NTHR) smem[i] = 0;
  __syncthreads();

  const int lane = tid & 63;
  const int wid  = tid >> 6;          // 16 waves, 32 output cols each
  const int l15  = lane & 15;
  const int khi  = lane >> 4;         // 0..3
  const int n0   = wid * 32;
  const int rowbase = blockIdx.x * RPB;

  unsigned short* slotBase = stage + wid * 3072;

  // A-frag LDS elem address: row l15, k = kc + khi*8 + j ; swizzle bits 3..5 by row
  const int aBase = l15 * U + khi * 8;
  const int aSwz  = (l15 & 7) << 3;

  // per-lane global bases for B tiles (nf=0 at n0+l15, nf=1 at n0+16+l15), k-contig
  const unsigned short* g0_0 = Wh0t + (size_t)(n0 + l15) * U + khi * 8;
  const unsigned short* g0_1 = g0_0 + (size_t)16 * U;
  const unsigned short* g1_0 = W1t + (size_t)(n0 + l15) * (2 * U) + khi * 8;
  const unsigned short* g1_1 = g1_0 + (size_t)16 * (2 * U);
  const unsigned short* g2_0 = W2t + (size_t)(n0 + l15) * (2 * U) + khi * 8;
  const unsigned short* g2_1 = g2_0 + (size_t)16 * (2 * U);

  float b1v[2], b2v[2];
#pragma unroll
  for (int nf = 0; nf < 2; ++nf){
    const int n = n0 + nf * 16 + l15;
    b1v[nf] = b1[n];
    b2v[nf] = b2[n];
  }

  f32x4 acc[2];

  for (int t = 0; t < SEQ; ++t){
    // ---------- layer 0: o0 = tanh(proj[tok] + s0 @ Wh0) ----------
    acc[0] = 0.0f; acc[1] = 0.0f;
    run_segment<16>(g0_0, g0_1, st0, st0, slotBase, aBase, aSwz, lane, acc);
    int tok[4];
#pragma unroll
    for (int j = 0; j < 4; ++j)
      tok[j] = tokens[(size_t)(rowbase + khi * 4 + j) * SEQ + t];
    __syncthreads();                 // everyone done reading st0
#pragma unroll
    for (int nf = 0; nf < 2; ++nf){
      const int col = n0 + nf * 16 + l15;
#pragma unroll
      for (int j = 0; j < 4; ++j){
        const int rr = khi * 4 + j;
        const float z = acc[nf][j] + proj[(size_t)tok[j] * U + col];
        st0[(rr * U + col) ^ ((rr & 7) << 3)] = f2bf(fast_tanh(z));
      }
    }
    __syncthreads();

    // ---------- layer 1: o1 = tanh([o0 | s1] @ [Wx1;Wh1] + b1) ----------
    acc[0] = 0.0f; acc[1] = 0.0f;
    run_segment<32>(g1_0, g1_1, st0, st1, slotBase, aBase, aSwz, lane, acc);
    __syncthreads();
#pragma unroll
    for (int nf = 0; nf < 2; ++nf){
      const int col = n0 + nf * 16 + l15;
#pragma unroll
      for (int j = 0; j < 4; ++j){
        const int rr = khi * 4 + j;
        st1[(rr * U + col) ^ ((rr & 7) << 3)] = f2bf(fast_tanh(acc[nf][j] + b1v[nf]));
      }
    }
    __syncthreads();

    // ---------- layer 2: o2 = tanh([o1 | s2] @ [Wx2;Wh2] + b2) ----------
    acc[0] = 0.0f; acc[1] = 0.0f;
    run_segment<32>(g2_0, g2_1, st1, st2, slotBase, aBase, aSwz, lane, acc);
    __syncthreads();
#pragma unroll
    for (int nf = 0; nf < 2; ++nf){
      const int col = n0 + nf * 16 + l15;
#pragma unroll
      for (int j = 0; j < 4; ++j){
        const int rr = khi * 4 + j;
        st2[(rr * U + col) ^ ((rr & 7) << 3)] = f2bf(fast_tanh(acc[nf][j] + b2v[nf]));
      }
    }
    __syncthreads();
  }

  // ---------- output: sigmoid(s2 @ Wout + bout), one wave per row ----------
  if (wid < RPB){
    const int r = wid;
    float v = 0.0f;
#pragma unroll
    for (int jj = 0; jj < 8; ++jj){
      const int n = lane + jj * 64;
      v += bf2f(st2[(r * U + n) ^ ((r & 7) << 3)]) * Wout[n];
    }
#pragma unroll
    for (int off = 32; off > 0; off >>= 1)
      v += __shfl_down(v, off, 64);
    if (lane == 0)
      out[rowbase + r] = 1.0f / (1.0f + __expf(-(v + bout[0])));
  }
}

extern "C" void kernel_launch(void* const* d_in, const int* in_sizes, int n_in,
                              void* d_out, int out_size, void* d_ws, size_t ws_size,
                              hipStream_t stream){
  (void)in_sizes; (void)n_in; (void)out_size; (void)ws_size;
  const int*   tokens = (const int*)  d_in[0];
  const float* emb  = (const float*)d_in[1];
  const float* Wx0  = (const float*)d_in[2];
  const float* Wh0  = (const float*)d_in[3];
  const float* b0   = (const float*)d_in[4];
  const float* Wx1  = (const float*)d_in[5];
  const float* Wh1  = (const float*)d_in[6];
  const float* b1   = (const float*)d_in[7];
  const float* Wx2  = (const float*)d_in[8];
  const float* Wh2  = (const float*)d_in[9];
  const float* b2   = (const float*)d_in[10];
  const float* Wout = (const float*)d_in[11];
  const float* bout = (const float*)d_in[12];

  char* ws = (char*)d_ws;
  float* proj = (float*)ws;                                   // 10000*512*4  = 20.48 MB
  unsigned short* Wh0t = (unsigned short*)(ws + (size_t)TW * U * 4);
  unsigned short* W1t  = Wh0t + (size_t)U * U;                // [512][1024]
  unsigned short* W2t  = W1t  + (size_t)U * 2 * U;

  proj_kernel<<<TW / 16, 256, 0, stream>>>(emb, Wx0, b0, proj);
  const int tblk = (U * U + 255) / 256;
  transpose_bf16<<<tblk, 256, 0, stream>>>(Wh0, Wh0t, U, U, U,     0);
  transpose_bf16<<<tblk, 256, 0, stream>>>(Wx1, W1t,  U, U, 2 * U, 0);
  transpose_bf16<<<tblk, 256, 0, stream>>>(Wh1, W1t,  U, U, 2 * U, U);
  transpose_bf16<<<tblk, 256, 0, stream>>>(Wx2, W2t,  U, U, 2 * U, 0);
  transpose_bf16<<<tblk, 256, 0, stream>>>(Wh2, W2t,  U, U, 2 * U, U);

  static const int kLds = 147456;   // 48 KiB states + 96 KiB staging rings
  (void)hipFuncSetAttribute((const void*)rnn_persist,
                            hipFuncAttributeMaxDynamicSharedMemorySize, kLds);
  rnn_persist<<<NBLK, NTHR, kLds, stream>>>(tokens, proj, Wh0t, W1t, W2t,
                                            b1, b2, Wout, bout, (float*)d_out);
}